// Round 3
// baseline (249.351 us; speedup 1.0000x reference)
//
#include <hip/hip_runtime.h>

#define HW   16384
#define WID  128
#define HEI  128
#define CIN  64
#define OCH  64
#define K2   9

// ---------------- kernel T: weight transpose -------------------------------
// wt4[(i4*64 + o)*4 + j] = w_dcn[o*576 + i4*4 + j]   (i = c*9+k, i4 = i/4)
__global__ __launch_bounds__(256) void ktrans(const float* __restrict__ wdcn,
                                              float* __restrict__ wt4) {
    int t = blockIdx.x * 256 + threadIdx.x;          // 0..36863
    int j = t & 3;
    int o = (t >> 2) & 63;
    int i4 = t >> 8;
    wt4[t] = wdcn[o * 576 + i4 * 4 + j];
}

// ---------------- kernel A: offset conv (C=64 -> 18, 3x3, pad 1) -----------
// thread = (pixel, ocg); ocg in {0,1,2} handles 6 output channels
__global__ __launch_bounds__(256) void koff(const float* __restrict__ x,
                                            const float* __restrict__ woff,
                                            const float* __restrict__ boff,
                                            float* __restrict__ offs) {
    int ocg = blockIdx.x >> 8;                         // uniform per block
    int pix = ((blockIdx.x & 255) << 8) + threadIdx.x; // 0..65535
    int b = pix >> 14;
    int hw = pix & (HW - 1);
    int h = hw >> 7, w = hw & (WID - 1);

    int   idxc[9];
    float msk[9];
#pragma unroll
    for (int t = 0; t < 9; t++) {
        int ys = h + t / 3 - 1;
        int xs = w + t % 3 - 1;
        bool ok = ((unsigned)ys < HEI) && ((unsigned)xs < WID);
        idxc[t] = ok ? ys * WID + xs : 0;
        msk[t] = ok ? 1.f : 0.f;
    }

    float acc[6] = {0.f, 0.f, 0.f, 0.f, 0.f, 0.f};
    const float* xb = x + (size_t)b * CIN * HW;
#pragma unroll 1
    for (int c = 0; c < CIN; c++) {
        float xv[9];
#pragma unroll
        for (int t = 0; t < 9; t++) xv[t] = xb[c * HW + idxc[t]] * msk[t];
        const float* wrow = woff + (size_t)ocg * 6 * CIN * 9 + c * 9; // uniform addr -> s_load
#pragma unroll
        for (int j = 0; j < 6; j++)
#pragma unroll
            for (int t = 0; t < 9; t++)
                acc[j] += xv[t] * wrow[j * CIN * 9 + t];
    }
#pragma unroll
    for (int j = 0; j < 6; j++) {
        int oc = ocg * 6 + j;
        offs[((size_t)b * 18 + oc) * HW + hw] = acc[j] + boff[oc];
    }
}

// ---------------- kernel B: deformable sample + contraction ----------------
// block = 256 threads, 16 consecutive-w pixels.
// Sampling: lane = (px | c4), covers 64 channels via cc loop; LDS patch[16][576+pad].
// GEMM: o = lane, wave handles 4 pixels; patch via LDS broadcast, weights float4 coalesced.
__global__ __launch_bounds__(256) void kdcn(const float* __restrict__ x,
                                            const float* __restrict__ offs,
                                            const float* __restrict__ wt4,
                                            const float* __restrict__ bdcn,
                                            float* __restrict__ conv) {
    __shared__ float patch[16][580];

    int tid = threadIdx.x;
    int lane = tid & 63, wave = tid >> 6;
    int px = lane & 15, c4 = lane >> 4;

    int pixg = blockIdx.x * 16;
    int b = pixg >> 14;              // uniform
    int hwb = pixg & (HW - 1);
    int h = hwb >> 7;                // uniform (16 | 128)
    int w0 = hwb & (WID - 1);
    int hw = hwb + px;
    int w = w0 + px;

    // 18 offset values for this pixel
    float offv[18];
    const float* op = offs + (size_t)b * 18 * HW + hw;
#pragma unroll
    for (int t = 0; t < 18; t++) offv[t] = op[t * HW];

    const float* xb0 = x + (size_t)b * CIN * HW;
#pragma unroll
    for (int tap = 0; tap < 9; tap++) {
        float py = offv[2 * tap]     + (float)(h + tap / 3 - 1);
        float pxf = offv[2 * tap + 1] + (float)(w + tap % 3 - 1);
        float y0f = floorf(py), x0f = floorf(pxf);
        float wy = py - y0f, wx = pxf - x0f;
        int y0 = (int)y0f, x0i = (int)x0f;
        // zero-padding bilinear: zero weight outside, clamp index for safe load
        float wy0 = ((unsigned)y0        < HEI) ? 1.f - wy : 0.f;
        float wy1 = ((unsigned)(y0 + 1)  < HEI) ? wy       : 0.f;
        float wx0 = ((unsigned)x0i       < WID) ? 1.f - wx : 0.f;
        float wx1 = ((unsigned)(x0i + 1) < WID) ? wx       : 0.f;
        int yc0 = min(max(y0, 0), HEI - 1) * WID;
        int yc1 = min(max(y0 + 1, 0), HEI - 1) * WID;
        int xc0 = min(max(x0i, 0), WID - 1);
        int xc1 = min(max(x0i + 1, 0), WID - 1);
        float w00 = wy0 * wx0, w01 = wy0 * wx1, w10 = wy1 * wx0, w11 = wy1 * wx1;
        int i00 = yc0 + xc0, i01 = yc0 + xc1, i10 = yc1 + xc0, i11 = yc1 + xc1;
#pragma unroll
        for (int cc = 0; cc < 4; cc++) {
            int c = cc * 16 + wave * 4 + c4;
            const float* xb = xb0 + c * HW;
            float v = w00 * xb[i00] + w01 * xb[i01] + w10 * xb[i10] + w11 * xb[i11];
            patch[px][c * 9 + tap] = v;
        }
    }
    __syncthreads();

    // contraction: out[o=lane] for 4 pixels of this wave
    float acc[4];
    float bias = bdcn[lane];
#pragma unroll
    for (int pp = 0; pp < 4; pp++) acc[pp] = bias;

    const float4* wt = (const float4*)wt4;
    int pxg = wave * 4;
#pragma unroll 2
    for (int i4 = 0; i4 < 144; i4++) {
        float4 wv = wt[i4 * 64 + lane];
#pragma unroll
        for (int pp = 0; pp < 4; pp++) {
            float4 pv = *(const float4*)&patch[pxg + pp][i4 * 4];
            acc[pp] += pv.x * wv.x + pv.y * wv.y + pv.z * wv.z + pv.w * wv.w;
        }
    }

    size_t obase = ((size_t)b * OCH + lane) * HW + hwb + pxg;
#pragma unroll
    for (int pp = 0; pp < 4; pp++) conv[obase + pp] = acc[pp];
}

// ---------------- kernel C: per-channel batch stats ------------------------
__global__ __launch_bounds__(256) void kstats(const float* __restrict__ conv,
                                              float* __restrict__ stats) {
    int c = blockIdx.x, tid = threadIdx.x;
    float s = 0.f, s2 = 0.f;
    for (int b = 0; b < 4; b++) {
        const float4* p = (const float4*)(conv + ((size_t)b * OCH + c) * HW);
        for (int i = tid; i < HW / 4; i += 256) {
            float4 v = p[i];
            s  += v.x + v.y + v.z + v.w;
            s2 += v.x * v.x + v.y * v.y + v.z * v.z + v.w * v.w;
        }
    }
    __shared__ float rs[256], rq[256];
    rs[tid] = s; rq[tid] = s2;
    __syncthreads();
    for (int st = 128; st > 0; st >>= 1) {
        if (tid < st) { rs[tid] += rs[tid + st]; rq[tid] += rq[tid + st]; }
        __syncthreads();
    }
    if (tid == 0) {
        float mean = rs[0] * (1.f / 65536.f);
        float var  = rq[0] * (1.f / 65536.f) - mean * mean;
        stats[c] = mean;
        stats[64 + c] = rsqrtf(var + 1e-5f);
    }
}

// ---------------- kernel D: normalize + affine + relu (in-place) -----------
__global__ __launch_bounds__(256) void kapply(float* __restrict__ conv,
                                              const float* __restrict__ stats,
                                              const float* __restrict__ gamma,
                                              const float* __restrict__ beta) {
    int t = blockIdx.x * 256 + threadIdx.x;   // < 1048576 float4s
    int c = (t >> 12) & 63;
    float mean = stats[c], rstd = stats[64 + c];
    float sc = rstd * gamma[c];
    float sh = beta[c] - mean * sc;
    float4 v = ((float4*)conv)[t];
    float4 r;
    r.x = fmaxf(v.x * sc + sh, 0.f);
    r.y = fmaxf(v.y * sc + sh, 0.f);
    r.z = fmaxf(v.z * sc + sh, 0.f);
    r.w = fmaxf(v.w * sc + sh, 0.f);
    ((float4*)conv)[t] = r;
}

// ---------------- launch ---------------------------------------------------
extern "C" void kernel_launch(void* const* d_in, const int* in_sizes, int n_in,
                              void* d_out, int out_size, void* d_ws, size_t ws_size,
                              hipStream_t stream) {
    const float* x     = (const float*)d_in[0];
    const float* woff  = (const float*)d_in[1];
    const float* boff  = (const float*)d_in[2];
    const float* wdcn  = (const float*)d_in[3];
    const float* bdcn  = (const float*)d_in[4];
    const float* gamma = (const float*)d_in[5];
    const float* beta  = (const float*)d_in[6];
    float* out = (float*)d_out;   // also holds pre-BN conv result

    float* ws = (float*)d_ws;
    float* offs  = ws;                 // 4*18*16384   = 1,179,648 floats
    float* wt4   = ws + 1179648;       // 576*64       =    36,864 floats
    float* stats = ws + 1216512;       // 128 floats
    // total ws: 1,216,640 floats = 4.87 MB

    hipLaunchKernelGGL(ktrans, dim3(144),  dim3(256), 0, stream, wdcn, wt4);
    hipLaunchKernelGGL(koff,   dim3(768),  dim3(256), 0, stream, x, woff, boff, offs);
    hipLaunchKernelGGL(kdcn,   dim3(4096), dim3(256), 0, stream, x, offs, wt4, bdcn, out);
    hipLaunchKernelGGL(kstats, dim3(64),   dim3(256), 0, stream, out, stats);
    hipLaunchKernelGGL(kapply, dim3(4096), dim3(256), 0, stream, out, stats, gamma, beta);
}

// Round 4
// 168.696 us; speedup vs baseline: 1.4781x; 1.4781x over previous
//
#include <hip/hip_runtime.h>

#define HW   16384
#define WID  128
#define HEI  128
#define CIN  64
#define OCH  64

typedef __attribute__((ext_vector_type(8))) short bf16x8;
typedef __attribute__((ext_vector_type(4))) float f32x4;

__device__ __forceinline__ unsigned short f2bf(float f) {
    unsigned u = __float_as_uint(f);
    u += 0x7FFF + ((u >> 16) & 1);          // RNE
    return (unsigned short)(u >> 16);
}

// ---------------- kernel T: pack w_dcn into B-fragment order (bf16) --------
// k-dim reordered: k = tap*64 + c.  Fragment (s, nt): lane l holds
// B[k = s*32 + (l>>4)*8 + j][o = nt*16 + (l&15)],  j = 0..7 contiguous.
// wpack[((s*4 + nt)*64 + l)*8 + j]
__global__ __launch_bounds__(256) void ktrans(const float* __restrict__ wdcn,
                                              unsigned short* __restrict__ wpack) {
    int t = blockIdx.x * 256 + threadIdx.x;   // 0..36863
    int j  = t & 7;
    int l  = (t >> 3) & 63;
    int nt = (t >> 9) & 3;
    int s  = t >> 11;                          // 0..17
    int k  = s * 32 + (l >> 4) * 8 + j;        // 0..575
    int o  = nt * 16 + (l & 15);
    int tap = k >> 6;                          // k = tap*64 + c
    int c   = k & 63;
    wpack[t] = f2bf(wdcn[o * 576 + c * 9 + tap]);
}

// ---------------- kernel A: offset conv (C=64 -> 18, 3x3, pad 1) -----------
__global__ __launch_bounds__(256) void koff(const float* __restrict__ x,
                                            const float* __restrict__ woff,
                                            const float* __restrict__ boff,
                                            float* __restrict__ offs) {
    int ocg = blockIdx.x >> 8;                         // uniform per block
    int pix = ((blockIdx.x & 255) << 8) + threadIdx.x; // 0..65535
    int b = pix >> 14;
    int hw = pix & (HW - 1);
    int h = hw >> 7, w = hw & (WID - 1);

    int   idxc[9];
    float msk[9];
#pragma unroll
    for (int t = 0; t < 9; t++) {
        int ys = h + t / 3 - 1;
        int xs = w + t % 3 - 1;
        bool ok = ((unsigned)ys < HEI) && ((unsigned)xs < WID);
        idxc[t] = ok ? ys * WID + xs : 0;
        msk[t] = ok ? 1.f : 0.f;
    }

    float acc[6] = {0.f, 0.f, 0.f, 0.f, 0.f, 0.f};
    const float* xb = x + (size_t)b * CIN * HW;
#pragma unroll 1
    for (int c = 0; c < CIN; c++) {
        float xv[9];
#pragma unroll
        for (int t = 0; t < 9; t++) xv[t] = xb[c * HW + idxc[t]] * msk[t];
        const float* wrow = woff + (size_t)ocg * 6 * CIN * 9 + c * 9;
#pragma unroll
        for (int j = 0; j < 6; j++)
#pragma unroll
            for (int t = 0; t < 9; t++)
                acc[j] += xv[t] * wrow[j * CIN * 9 + t];
    }
#pragma unroll
    for (int j = 0; j < 6; j++) {
        int oc = ocg * 6 + j;
        offs[((size_t)b * 18 + oc) * HW + hw] = acc[j] + boff[oc];
    }
}

// ---------------- kernel B: deformable sample + MFMA contraction -----------
// block = 256 threads = 4 waves, 32 consecutive-w pixels.
// LDS: patch bf16 [32 px][576 k], pitch 1152 B, XOR-swizzled by (px&7)<<4;
//      tapinfo [288][8] u32 at +36864.
__global__ __launch_bounds__(256, 3) void kdcn(const float* __restrict__ x,
                                               const float* __restrict__ offs,
                                               const unsigned short* __restrict__ wpack,
                                               const float* __restrict__ bdcn,
                                               float* __restrict__ conv) {
    __shared__ __align__(16) unsigned char smem[46080];

    int tid = threadIdx.x;
    int lane = tid & 63, wave = tid >> 6;
    int lr = lane & 15, hi = lane >> 4;

    int pixg = blockIdx.x * 32;
    int b = pixg >> 14;                 // uniform
    int hwb = pixg & (HW - 1);
    int h = hwb >> 7;                   // uniform (32 | 128)
    int w0 = hwb & (WID - 1);

    // ---- phase A: per-(px,tap) bilinear indices + validity-folded weights
    int* ti = (int*)(smem + 36864);
    for (int item = tid; item < 288; item += 256) {
        int ppx = item / 9, tap = item - ppx * 9;
        int hw = hwb + ppx;
        float dy = offs[((size_t)b * 18 + tap * 2) * HW + hw];
        float dx = offs[((size_t)b * 18 + tap * 2 + 1) * HW + hw];
        float py  = dy + (float)(h + tap / 3 - 1);
        float pxf = dx + (float)(w0 + ppx + tap % 3 - 1);
        float y0f = floorf(py), x0f = floorf(pxf);
        float wy = py - y0f, wx = pxf - x0f;
        int y0 = (int)y0f, x0 = (int)x0f;
        float wy0 = ((unsigned)y0       < HEI) ? 1.f - wy : 0.f;
        float wy1 = ((unsigned)(y0 + 1) < HEI) ? wy       : 0.f;
        float wx0 = ((unsigned)x0       < WID) ? 1.f - wx : 0.f;
        float wx1 = ((unsigned)(x0 + 1) < WID) ? wx       : 0.f;
        int yc0 = min(max(y0, 0),     HEI - 1) * WID;
        int yc1 = min(max(y0 + 1, 0), HEI - 1) * WID;
        int xc0 = min(max(x0, 0),     WID - 1);
        int xc1 = min(max(x0 + 1, 0), WID - 1);
        int* t8 = ti + item * 8;
        t8[0] = yc0 + xc0; t8[1] = yc0 + xc1; t8[2] = yc1 + xc0; t8[3] = yc1 + xc1;
        float* f8 = (float*)t8;
        f8[4] = wy0 * wx0; f8[5] = wy0 * wx1; f8[6] = wy1 * wx0; f8[7] = wy1 * wx1;
    }
    __syncthreads();

    // ---- B fragments (18 K-steps for this wave's 16 outputs), overlap with
    // sampling; bias for o = wave*16 + lr
    bf16x8 bfrag[18];
    const unsigned short* wp = wpack + (size_t)(wave * 64 + lane) * 8;
#pragma unroll
    for (int s = 0; s < 18; s++)
        bfrag[s] = *(const bf16x8*)(wp + (size_t)s * 2048);
    float bias = bdcn[wave * 16 + lr];

    // ---- phase B: gather-sample 8 channels x 9 taps, pack bf16x8 into LDS
    {
        int px = tid & 31, q = tid >> 5;           // q: channel group (8 ch)
        const float* xb0 = x + (size_t)b * CIN * HW + (size_t)q * 8 * HW;
        unsigned swz = (unsigned)((px & 7) << 4);
        unsigned char* prow = smem + px * 1152;
#pragma unroll
        for (int tap = 0; tap < 9; tap++) {
            const int* t8 = ti + (px * 9 + tap) * 8;
            int i00 = t8[0], i01 = t8[1], i10 = t8[2], i11 = t8[3];
            const float* f8 = (const float*)t8;
            float w00 = f8[4], w01 = f8[5], w10 = f8[6], w11 = f8[7];
            bf16x8 v;
#pragma unroll
            for (int cc = 0; cc < 8; cc++) {
                const float* xb = xb0 + (size_t)cc * HW;
                float sv = w00 * xb[i00] + w01 * xb[i01]
                         + w10 * xb[i10] + w11 * xb[i11];
                v[cc] = (short)f2bf(sv);
            }
            *(bf16x8*)(prow + ((unsigned)(tap * 128 + q * 16) ^ swz)) = v;
        }
    }
    __syncthreads();

    // ---- MFMA: D[32 px][64 o], wave owns ntile = wave (o = wave*16+lr)
    f32x4 acc0 = {bias, bias, bias, bias};
    f32x4 acc1 = acc0;
    unsigned swzr = (unsigned)((lr & 7) << 4);     // (px&7) same for lr, lr+16
#pragma unroll
    for (int s = 0; s < 18; s++) {
        unsigned inblk = (unsigned)((s >> 1) * 128)
                       + (((unsigned)((s & 1) * 64 + hi * 16)) ^ swzr);
        bf16x8 a0 = *(const bf16x8*)(smem + lr * 1152 + inblk);
        bf16x8 a1 = *(const bf16x8*)(smem + (16 + lr) * 1152 + inblk);
        acc0 = __builtin_amdgcn_mfma_f32_16x16x32_bf16(a0, bfrag[s], acc0, 0, 0, 0);
        acc1 = __builtin_amdgcn_mfma_f32_16x16x32_bf16(a1, bfrag[s], acc1, 0, 0, 0);
    }
    __syncthreads();

    // ---- epilogue: transpose via LDS, coalesced float4 stores
    float* ldsC = (float*)smem;                    // [64][33]
    {
        int o = wave * 16 + lr;
        int pxb = hi * 4;
#pragma unroll
        for (int r = 0; r < 4; r++) {
            ldsC[o * 33 + pxb + r]      = acc0[r];
            ldsC[o * 33 + 16 + pxb + r] = acc1[r];
        }
    }
    __syncthreads();
    {
        int px4 = (tid & 7) * 4;
#pragma unroll
        for (int pass = 0; pass < 2; pass++) {
            int oo = (tid >> 3) + pass * 32;
            float4 v;
            v.x = ldsC[oo * 33 + px4];
            v.y = ldsC[oo * 33 + px4 + 1];
            v.z = ldsC[oo * 33 + px4 + 2];
            v.w = ldsC[oo * 33 + px4 + 3];
            *(float4*)(conv + ((size_t)b * OCH + oo) * HW + hwb + px4) = v;
        }
    }
}

// ---------------- kernel C: per-channel batch stats ------------------------
__global__ __launch_bounds__(256) void kstats(const float* __restrict__ conv,
                                              float* __restrict__ stats) {
    int c = blockIdx.x, tid = threadIdx.x;
    float s = 0.f, s2 = 0.f;
    for (int b = 0; b < 4; b++) {
        const float4* p = (const float4*)(conv + ((size_t)b * OCH + c) * HW);
        for (int i = tid; i < HW / 4; i += 256) {
            float4 v = p[i];
            s  += v.x + v.y + v.z + v.w;
            s2 += v.x * v.x + v.y * v.y + v.z * v.z + v.w * v.w;
        }
    }
    __shared__ float rs[256], rq[256];
    rs[tid] = s; rq[tid] = s2;
    __syncthreads();
    for (int st = 128; st > 0; st >>= 1) {
        if (tid < st) { rs[tid] += rs[tid + st]; rq[tid] += rq[tid + st]; }
        __syncthreads();
    }
    if (tid == 0) {
        float mean = rs[0] * (1.f / 65536.f);
        float var  = rq[0] * (1.f / 65536.f) - mean * mean;
        stats[c] = mean;
        stats[64 + c] = rsqrtf(var + 1e-5f);
    }
}

// ---------------- kernel D: normalize + affine + relu (in-place) -----------
__global__ __launch_bounds__(256) void kapply(float* __restrict__ conv,
                                              const float* __restrict__ stats,
                                              const float* __restrict__ gamma,
                                              const float* __restrict__ beta) {
    int t = blockIdx.x * 256 + threadIdx.x;   // < 1048576 float4s
    int c = (t >> 12) & 63;
    float mean = stats[c], rstd = stats[64 + c];
    float sc = rstd * gamma[c];
    float sh = beta[c] - mean * sc;
    float4 v = ((float4*)conv)[t];
    float4 r;
    r.x = fmaxf(v.x * sc + sh, 0.f);
    r.y = fmaxf(v.y * sc + sh, 0.f);
    r.z = fmaxf(v.z * sc + sh, 0.f);
    r.w = fmaxf(v.w * sc + sh, 0.f);
    ((float4*)conv)[t] = r;
}

// ---------------- launch ---------------------------------------------------
extern "C" void kernel_launch(void* const* d_in, const int* in_sizes, int n_in,
                              void* d_out, int out_size, void* d_ws, size_t ws_size,
                              hipStream_t stream) {
    const float* x     = (const float*)d_in[0];
    const float* woff  = (const float*)d_in[1];
    const float* boff  = (const float*)d_in[2];
    const float* wdcn  = (const float*)d_in[3];
    const float* bdcn  = (const float*)d_in[4];
    const float* gamma = (const float*)d_in[5];
    const float* beta  = (const float*)d_in[6];
    float* out = (float*)d_out;   // also holds pre-BN conv result

    float* ws = (float*)d_ws;
    float*          offs  = ws;                         // 1,179,648 floats
    unsigned short* wpack = (unsigned short*)(ws + 1179648); // 36,864 ushorts
    float*          stats = ws + 1179648 + 18432;       // 128 floats
    // total ws: ~4.8 MB

    hipLaunchKernelGGL(ktrans, dim3(144),  dim3(256), 0, stream, wdcn, wpack);
    hipLaunchKernelGGL(koff,   dim3(768),  dim3(256), 0, stream, x, woff, boff, offs);
    hipLaunchKernelGGL(kdcn,   dim3(2048), dim3(256), 0, stream, x, offs, wpack, bdcn, out);
    hipLaunchKernelGGL(kstats, dim3(64),   dim3(256), 0, stream, out, stats);
    hipLaunchKernelGGL(kapply, dim3(4096), dim3(256), 0, stream, out, stats, gamma, beta);
}

// Round 7
// 102.881 us; speedup vs baseline: 2.4237x; 1.6397x over previous
//
#include <hip/hip_runtime.h>

#define HW   16384
#define WID  128
#define HEI  128
#define CIN  64
#define OCH  64

typedef __attribute__((ext_vector_type(8))) short bf16x8;
typedef __attribute__((ext_vector_type(4))) float f32x4;
typedef __attribute__((ext_vector_type(4))) int   i32x4;

__device__ __forceinline__ unsigned short f2bf(float f) {
    unsigned u = __float_as_uint(f);
    u += 0x7FFF + ((u >> 16) & 1);          // RNE
    return (unsigned short)(u >> 16);
}
__device__ __forceinline__ float bf2f(short s) {
    return __uint_as_float(((unsigned)(unsigned short)s) << 16);
}

// ---------------- kernel X: x NCHW f32 -> NHWC bf16 ------------------------
__global__ __launch_bounds__(256) void kxt(const float* __restrict__ x,
                                           unsigned short* __restrict__ xt) {
    int gp = blockIdx.x * 256 + threadIdx.x;   // 0..65535 = (b, hw)
    int b = gp >> 14;
    int hw = gp & (HW - 1);
    const float* xb = x + (size_t)b * CIN * HW + hw;
    unsigned short* o = xt + ((size_t)gp << 6);
#pragma unroll
    for (int c8 = 0; c8 < 8; c8++) {
        bf16x8 v;
#pragma unroll
        for (int j = 0; j < 8; j++)
            v[j] = (short)f2bf(xb[(size_t)(c8 * 8 + j) * HW]);
        *(bf16x8*)(o + c8 * 8) = v;
    }
}

// ---------------- kernel T: pack w_dcn into B-fragment order (bf16) --------
// k = tap*64 + c.  Fragment (s, nt): lane l holds
// B[k = s*32 + (l>>4)*8 + j][o = nt*16 + (l&15)],  j = 0..7 contiguous.
__global__ __launch_bounds__(256) void ktrans(const float* __restrict__ wdcn,
                                              unsigned short* __restrict__ wpack) {
    int t = blockIdx.x * 256 + threadIdx.x;   // 0..36863
    int j  = t & 7;
    int l  = (t >> 3) & 63;
    int nt = (t >> 9) & 3;
    int s  = t >> 11;                          // 0..17
    int k  = s * 32 + (l >> 4) * 8 + j;        // 0..575
    int o  = nt * 16 + (l & 15);
    int tap = k >> 6;
    int c   = k & 63;
    wpack[t] = f2bf(wdcn[o * 576 + c * 9 + tap]);
}

// ---------------- kernel A: offset conv -> packed bf16 (dy,dx) per tap -----
__global__ __launch_bounds__(256) void koff(const float* __restrict__ x,
                                            const float* __restrict__ woff,
                                            const float* __restrict__ boff,
                                            unsigned* __restrict__ offp) {
    int ocg = blockIdx.x >> 8;                         // 0..2, uniform
    int pix = ((blockIdx.x & 255) << 8) + threadIdx.x; // 0..65535
    int b = pix >> 14;
    int hw = pix & (HW - 1);
    int h = hw >> 7, w = hw & (WID - 1);

    int   idxc[9];
    float msk[9];
#pragma unroll
    for (int t = 0; t < 9; t++) {
        int ys = h + t / 3 - 1;
        int xs = w + t % 3 - 1;
        bool ok = ((unsigned)ys < HEI) && ((unsigned)xs < WID);
        idxc[t] = ok ? ys * WID + xs : 0;
        msk[t] = ok ? 1.f : 0.f;
    }

    float acc[6];
#pragma unroll
    for (int j = 0; j < 6; j++) acc[j] = boff[ocg * 6 + j];
    const float* xb = x + (size_t)b * CIN * HW;
#pragma unroll 1
    for (int c = 0; c < CIN; c++) {
        float xv[9];
#pragma unroll
        for (int t = 0; t < 9; t++) xv[t] = xb[c * HW + idxc[t]] * msk[t];
        const float* wrow = woff + (size_t)ocg * 6 * CIN * 9 + c * 9;
#pragma unroll
        for (int j = 0; j < 6; j++)
#pragma unroll
            for (int t = 0; t < 9; t++)
                acc[j] += xv[t] * wrow[j * CIN * 9 + t];
    }
    // oc = ocg*6 + j ; tap = oc>>1 ; dy = even, dx = odd
#pragma unroll
    for (int t2 = 0; t2 < 3; t2++) {
        int tap = ocg * 3 + t2;
        unsigned u = (unsigned)f2bf(acc[2 * t2])
                   | ((unsigned)f2bf(acc[2 * t2 + 1]) << 16);
        offp[((size_t)b * 9 + tap) * HW + hw] = u;
    }
}

// ---------------- kernel B: deformable sample + MFMA contraction -----------
// block = 4 waves, 32 consecutive-w pixels.
// LDS: patch bf16 [32 px][576 k] pitch 1152B, XOR-swizzled by (px&7)<<4;
//      tapinfo [288][8] u32 at +36864 (4 NHWC byte-offsets + 4 weights).
__global__ __launch_bounds__(256, 3) void kdcn(const unsigned short* __restrict__ xt,
                                               const unsigned* __restrict__ offp,
                                               const unsigned short* __restrict__ wpack,
                                               const float* __restrict__ bdcn,
                                               float* __restrict__ conv) {
    __shared__ __align__(16) unsigned char smem[46080];

    int tid = threadIdx.x;
    int lane = tid & 63, wave = tid >> 6;
    int lr = lane & 15, hi = lane >> 4;

    int pixg = blockIdx.x * 32;
    int b = pixg >> 14;                 // uniform
    int hwb = pixg & (HW - 1);
    int h = hwb >> 7;                   // uniform (32 | 128)
    int w0 = hwb & (WID - 1);

    // ---- phase A: per-(px,tap) NHWC byte offsets + validity-folded weights
    int* ti = (int*)(smem + 36864);
    for (int item = tid; item < 288; item += 256) {
        int ppx = item / 9, tap = item - ppx * 9;
        unsigned u = offp[((size_t)b * 9 + tap) * HW + hwb + ppx];
        float dy = __uint_as_float(u << 16);
        float dx = __uint_as_float(u & 0xffff0000u);
        float py  = dy + (float)(h + tap / 3 - 1);
        float pxf = dx + (float)(w0 + ppx + tap % 3 - 1);
        float y0f = floorf(py), x0f = floorf(pxf);
        float wy = py - y0f, wx = pxf - x0f;
        int y0 = (int)y0f, x0 = (int)x0f;
        float wy0 = ((unsigned)y0       < HEI) ? 1.f - wy : 0.f;
        float wy1 = ((unsigned)(y0 + 1) < HEI) ? wy       : 0.f;
        float wx0 = ((unsigned)x0       < WID) ? 1.f - wx : 0.f;
        float wx1 = ((unsigned)(x0 + 1) < WID) ? wx       : 0.f;
        int yc0 = min(max(y0, 0),     HEI - 1) * WID;
        int yc1 = min(max(y0 + 1, 0), HEI - 1) * WID;
        int xc0 = min(max(x0, 0),     WID - 1);
        int xc1 = min(max(x0 + 1, 0), WID - 1);
        int* t8 = ti + item * 8;
        t8[0] = (yc0 + xc0) << 7;      // byte offset into NHWC bf16 (128B/px)
        t8[1] = (yc0 + xc1) << 7;
        t8[2] = (yc1 + xc0) << 7;
        t8[3] = (yc1 + xc1) << 7;
        float* f8 = (float*)t8;
        f8[4] = wy0 * wx0; f8[5] = wy0 * wx1; f8[6] = wy1 * wx0; f8[7] = wy1 * wx1;
    }
    __syncthreads();

    // ---- B fragments + bias (o = wave*16 + lr)
    bf16x8 bfrag[18];
    const unsigned short* wp = wpack + (size_t)(wave * 64 + lane) * 8;
#pragma unroll
    for (int s = 0; s < 18; s++)
        bfrag[s] = *(const bf16x8*)(wp + (size_t)s * 2048);
    float bias = bdcn[wave * 16 + lr];

    // ---- phase B: 8 lanes per px; each lane owns 8 channels, loops 9 taps
    {
        int g = lane >> 3;                       // px = wave*8 + g
        int sub = lane & 7;                      // channel group
        int px = wave * 8 + g;
        const unsigned char* xtb =
            (const unsigned char*)xt + (((size_t)b * HW) << 7) + sub * 16;
        unsigned char* prow = smem + px * 1152;
        unsigned swz = (unsigned)((px & 7) << 4);
        const int* tbase = ti + px * 72;
#pragma unroll
        for (int tap = 0; tap < 9; tap++) {
            i32x4 t4 = *(const i32x4*)(tbase + tap * 8);
            f32x4 w4 = *(const f32x4*)(tbase + tap * 8 + 4);
            bf16x8 c00 = *(const bf16x8*)(xtb + t4[0]);
            bf16x8 c01 = *(const bf16x8*)(xtb + t4[1]);
            bf16x8 c10 = *(const bf16x8*)(xtb + t4[2]);
            bf16x8 c11 = *(const bf16x8*)(xtb + t4[3]);
            bf16x8 v;
#pragma unroll
            for (int j = 0; j < 8; j++) {
                float sv = w4[0] * bf2f(c00[j]) + w4[1] * bf2f(c01[j])
                         + w4[2] * bf2f(c10[j]) + w4[3] * bf2f(c11[j]);
                v[j] = (short)f2bf(sv);
            }
            *(bf16x8*)(prow + ((unsigned)(tap * 128 + sub * 16) ^ swz)) = v;
        }
    }
    __syncthreads();

    // ---- MFMA: D[32 px][64 o], wave owns o-tile = wave
    f32x4 acc0 = {bias, bias, bias, bias};
    f32x4 acc1 = acc0;
    unsigned swzr = (unsigned)((lr & 7) << 4);
#pragma unroll
    for (int s = 0; s < 18; s++) {
        unsigned inblk = (unsigned)((s >> 1) * 128)
                       + (((unsigned)((s & 1) * 64 + hi * 16)) ^ swzr);
        bf16x8 a0 = *(const bf16x8*)(smem + lr * 1152 + inblk);
        bf16x8 a1 = *(const bf16x8*)(smem + (16 + lr) * 1152 + inblk);
        acc0 = __builtin_amdgcn_mfma_f32_16x16x32_bf16(a0, bfrag[s], acc0, 0, 0, 0);
        acc1 = __builtin_amdgcn_mfma_f32_16x16x32_bf16(a1, bfrag[s], acc1, 0, 0, 0);
    }
    __syncthreads();

    // ---- epilogue: transpose via LDS, coalesced float4 stores
    float* ldsC = (float*)smem;                    // [64][33]
    {
        int o = wave * 16 + lr;
        int pxb = hi * 4;
#pragma unroll
        for (int r = 0; r < 4; r++) {
            ldsC[o * 33 + pxb + r]      = acc0[r];
            ldsC[o * 33 + 16 + pxb + r] = acc1[r];
        }
    }
    __syncthreads();
    {
        int px4 = (tid & 7) * 4;
#pragma unroll
        for (int pass = 0; pass < 2; pass++) {
            int oo = (tid >> 3) + pass * 32;
            float4 v;
            v.x = ldsC[oo * 33 + px4];
            v.y = ldsC[oo * 33 + px4 + 1];
            v.z = ldsC[oo * 33 + px4 + 2];
            v.w = ldsC[oo * 33 + px4 + 3];
            *(float4*)(conv + ((size_t)b * OCH + oo) * HW + hwb + px4) = v;
        }
    }
}

// ---------------- kernel C: per-channel batch stats ------------------------
__global__ __launch_bounds__(256) void kstats(const float* __restrict__ conv,
                                              float* __restrict__ stats) {
    int c = blockIdx.x, tid = threadIdx.x;
    float s = 0.f, s2 = 0.f;
    for (int b = 0; b < 4; b++) {
        const float4* p = (const float4*)(conv + ((size_t)b * OCH + c) * HW);
        for (int i = tid; i < HW / 4; i += 256) {
            float4 v = p[i];
            s  += v.x + v.y + v.z + v.w;
            s2 += v.x * v.x + v.y * v.y + v.z * v.z + v.w * v.w;
        }
    }
    __shared__ float rs[256], rq[256];
    rs[tid] = s; rq[tid] = s2;
    __syncthreads();
    for (int st = 128; st > 0; st >>= 1) {
        if (tid < st) { rs[tid] += rs[tid + st]; rq[tid] += rq[tid + st]; }
        __syncthreads();
    }
    if (tid == 0) {
        float mean = rs[0] * (1.f / 65536.f);
        float var  = rq[0] * (1.f / 65536.f) - mean * mean;
        stats[c] = mean;
        stats[64 + c] = rsqrtf(var + 1e-5f);
    }
}

// ---------------- kernel D: normalize + affine + relu (in-place) -----------
__global__ __launch_bounds__(256) void kapply(float* __restrict__ conv,
                                              const float* __restrict__ stats,
                                              const float* __restrict__ gamma,
                                              const float* __restrict__ beta) {
    int t = blockIdx.x * 256 + threadIdx.x;   // < 1048576 float4s
    int c = (t >> 12) & 63;
    float mean = stats[c], rstd = stats[64 + c];
    float sc = rstd * gamma[c];
    float sh = beta[c] - mean * sc;
    float4 v = ((float4*)conv)[t];
    float4 r;
    r.x = fmaxf(v.x * sc + sh, 0.f);
    r.y = fmaxf(v.y * sc + sh, 0.f);
    r.z = fmaxf(v.z * sc + sh, 0.f);
    r.w = fmaxf(v.w * sc + sh, 0.f);
    ((float4*)conv)[t] = r;
}

// ---------------- launch ---------------------------------------------------
extern "C" void kernel_launch(void* const* d_in, const int* in_sizes, int n_in,
                              void* d_out, int out_size, void* d_ws, size_t ws_size,
                              hipStream_t stream) {
    const float* x     = (const float*)d_in[0];
    const float* woff  = (const float*)d_in[1];
    const float* boff  = (const float*)d_in[2];
    const float* wdcn  = (const float*)d_in[3];
    const float* bdcn  = (const float*)d_in[4];
    const float* gamma = (const float*)d_in[5];
    const float* beta  = (const float*)d_in[6];
    float* out = (float*)d_out;   // also holds pre-BN conv result

    // workspace layout (bytes): xt 8 MB | offp 2.25 MB | wpack 72 KB | stats
    unsigned char* ws = (unsigned char*)d_ws;
    unsigned short* xt    = (unsigned short*)ws;              // 4,194,304 ush
    unsigned*       offp  = (unsigned*)(ws + 8388608);        //   589,824 u32
    unsigned short* wpack = (unsigned short*)(ws + 10747904); //    36,864 ush
    float*          stats = (float*)(ws + 10821632);          //       128 f
    // total ~10.33 MB

    hipLaunchKernelGGL(kxt,    dim3(256),  dim3(256), 0, stream, x, xt);
    hipLaunchKernelGGL(ktrans, dim3(144),  dim3(256), 0, stream, wdcn, wpack);
    hipLaunchKernelGGL(koff,   dim3(768),  dim3(256), 0, stream, x, woff, boff, offp);
    hipLaunchKernelGGL(kdcn,   dim3(2048), dim3(256), 0, stream, xt, offp, wpack, bdcn, out);
    hipLaunchKernelGGL(kstats, dim3(64),   dim3(256), 0, stream, out, stats);
    hipLaunchKernelGGL(kapply, dim3(4096), dim3(256), 0, stream, out, stats, gamma, beta);
}

// Round 8
// 76.935 us; speedup vs baseline: 3.2411x; 1.3372x over previous
//
#include <hip/hip_runtime.h>

#define HW   16384
#define WID  128
#define HEI  128
#define CIN  64
#define OCH  64

typedef __attribute__((ext_vector_type(8))) short bf16x8;
typedef __attribute__((ext_vector_type(4))) float f32x4;
typedef __attribute__((ext_vector_type(4))) int   i32x4;

__device__ __forceinline__ unsigned short f2bf(float f) {
    unsigned u = __float_as_uint(f);
    u += 0x7FFF + ((u >> 16) & 1);          // RNE
    return (unsigned short)(u >> 16);
}
__device__ __forceinline__ float bf2f(short s) {
    return __uint_as_float(((unsigned)(unsigned short)s) << 16);
}

// ---------------- kernel X: x NCHW f32 -> NHWC bf16 ------------------------
__global__ __launch_bounds__(256) void kxt(const float* __restrict__ x,
                                           unsigned short* __restrict__ xt) {
    int gp = blockIdx.x * 256 + threadIdx.x;   // 0..65535 = (b, hw)
    int b = gp >> 14;
    int hw = gp & (HW - 1);
    const float* xb = x + (size_t)b * CIN * HW + hw;
    unsigned short* o = xt + ((size_t)gp << 6);
#pragma unroll
    for (int c8 = 0; c8 < 8; c8++) {
        bf16x8 v;
#pragma unroll
        for (int j = 0; j < 8; j++)
            v[j] = (short)f2bf(xb[(size_t)(c8 * 8 + j) * HW]);
        *(bf16x8*)(o + c8 * 8) = v;
    }
}

// ---------------- kernel P: pack w_dcn AND w_off into B-fragment order -----
// k = tap*64 + c.  Fragment (s, nt): lane l holds
// B[k = s*32 + (l>>4)*8 + j][o = nt*16 + (l&15)],  j = 0..7 contiguous.
// wpack:    18 s x 4 nt (64 outs)   -> 36864 ushorts
// woffpack: 18 s x 2 nt (18 outs,   -> 18432 ushorts, zero-padded o>=18)
__global__ __launch_bounds__(256) void kpack(const float* __restrict__ wdcn,
                                             const float* __restrict__ woff,
                                             unsigned short* __restrict__ wpack,
                                             unsigned short* __restrict__ woffpack) {
    int t = blockIdx.x * 256 + threadIdx.x;   // 0..55295
    if (t < 36864) {
        int j  = t & 7;
        int l  = (t >> 3) & 63;
        int nt = (t >> 9) & 3;
        int s  = t >> 11;                      // 0..17
        int k  = s * 32 + (l >> 4) * 8 + j;
        int o  = nt * 16 + (l & 15);
        int tap = k >> 6, c = k & 63;
        wpack[t] = f2bf(wdcn[o * 576 + c * 9 + tap]);
    } else {
        int u  = t - 36864;                    // 0..18431
        int j  = u & 7;
        int l  = (u >> 3) & 63;
        int nt = (u >> 9) & 1;
        int s  = u >> 10;                      // 0..17
        int k  = s * 32 + (l >> 4) * 8 + j;
        int o  = nt * 16 + (l & 15);
        int tap = k >> 6, c = k & 63;
        float v = (o < 18) ? woff[o * 576 + c * 9 + tap] : 0.f;
        woffpack[u] = f2bf(v);
    }
}

// ---------------- kernel B: offset conv + deformable sample + MFMA ---------
// block = 4 waves, 32 consecutive-w pixels.
// LDS: patch bf16 [32 px][576 k] pitch 1152B, XOR-swizzled by (px&7)<<4 (0..36863)
//      tapinfo [288][8] u32 (36864..46079)
//      offLds f32 [32 px][18 oc]   (46080..48383)
__global__ __launch_bounds__(256, 3) void kdcn(const unsigned short* __restrict__ xt,
                                               const unsigned short* __restrict__ wpack,
                                               const unsigned short* __restrict__ woffpack,
                                               const float* __restrict__ boff,
                                               const float* __restrict__ bdcn,
                                               float* __restrict__ conv) {
    __shared__ __align__(16) unsigned char smem[48384];

    int tid = threadIdx.x;
    int lane = tid & 63, wave = tid >> 6;
    int lr = lane & 15, hi = lane >> 4;

    int pixg = blockIdx.x * 32;
    int b = pixg >> 14;                 // uniform
    int hwb = pixg & (HW - 1);
    int h = hwb >> 7;                   // uniform (32 | 128)
    int w0 = hwb & (WID - 1);

    // ---- phase 0: stage REGULAR 3x3 patch (zero-padded) into LDS ----------
    {
        int g = lane >> 3, sub = lane & 7;
        int px = wave * 8 + g;
        int w = w0 + px;
        const unsigned char* xtb =
            (const unsigned char*)xt + (((size_t)b * HW) << 7) + sub * 16;
        unsigned char* prow = smem + px * 1152;
        unsigned swz = (unsigned)((px & 7) << 4);
#pragma unroll
        for (int tap = 0; tap < 9; tap++) {
            int sy = h + tap / 3 - 1;
            int sx = w + tap % 3 - 1;
            bool ok = ((unsigned)sy < HEI) && ((unsigned)sx < WID);
            bf16x8 v = {0, 0, 0, 0, 0, 0, 0, 0};
            if (ok) v = *(const bf16x8*)(xtb + ((sy * WID + sx) << 7));
            *(bf16x8*)(prow + ((unsigned)(tap * 128 + sub * 16) ^ swz)) = v;
        }
    }
    __syncthreads();

    // ---- phase 0b: offset conv via MFMA; D[32 px][18 oc] -> offLds --------
    {
        int mw = wave & 1, nw = wave >> 1;
        int oc = nw * 16 + lr;
        float ob = (oc < 18) ? boff[oc] : 0.f;
        f32x4 oacc = {ob, ob, ob, ob};
        unsigned swzr = (unsigned)((lr & 7) << 4);
        const unsigned short* wop = woffpack + (size_t)(nw * 64 + lane) * 8;
        int arow = (mw * 16 + lr) * 1152;
#pragma unroll
        for (int s = 0; s < 18; s++) {
            unsigned inblk = (unsigned)((s >> 1) * 128)
                           + (((unsigned)((s & 1) * 64 + hi * 16)) ^ swzr);
            bf16x8 a  = *(const bf16x8*)(smem + arow + inblk);
            bf16x8 wf = *(const bf16x8*)(wop + (size_t)s * 1024);
            oacc = __builtin_amdgcn_mfma_f32_16x16x32_bf16(a, wf, oacc, 0, 0, 0);
        }
        float* offLds = (float*)(smem + 46080);
        if (oc < 18) {
#pragma unroll
            for (int r = 0; r < 4; r++)
                offLds[(mw * 16 + hi * 4 + r) * 18 + oc] = oacc[r];
        }
    }
    __syncthreads();

    // ---- phase A: per-(px,tap) NHWC byte offsets + validity-folded weights
    int* ti = (int*)(smem + 36864);
    {
        const float* offLds = (const float*)(smem + 46080);
        for (int item = tid; item < 288; item += 256) {
            int ppx = item / 9, tap = item - ppx * 9;
            float dy = offLds[ppx * 18 + tap * 2];
            float dx = offLds[ppx * 18 + tap * 2 + 1];
            float py  = dy + (float)(h + tap / 3 - 1);
            float pxf = dx + (float)(w0 + ppx + tap % 3 - 1);
            float y0f = floorf(py), x0f = floorf(pxf);
            float wy = py - y0f, wx = pxf - x0f;
            int y0 = (int)y0f, x0 = (int)x0f;
            float wy0 = ((unsigned)y0       < HEI) ? 1.f - wy : 0.f;
            float wy1 = ((unsigned)(y0 + 1) < HEI) ? wy       : 0.f;
            float wx0 = ((unsigned)x0       < WID) ? 1.f - wx : 0.f;
            float wx1 = ((unsigned)(x0 + 1) < WID) ? wx       : 0.f;
            int yc0 = min(max(y0, 0),     HEI - 1) * WID;
            int yc1 = min(max(y0 + 1, 0), HEI - 1) * WID;
            int xc0 = min(max(x0, 0),     WID - 1);
            int xc1 = min(max(x0 + 1, 0), WID - 1);
            int* t8 = ti + item * 8;
            t8[0] = (yc0 + xc0) << 7;      // byte offset into NHWC bf16
            t8[1] = (yc0 + xc1) << 7;
            t8[2] = (yc1 + xc0) << 7;
            t8[3] = (yc1 + xc1) << 7;
            float* f8 = (float*)t8;
            f8[4] = wy0 * wx0; f8[5] = wy0 * wx1;
            f8[6] = wy1 * wx0; f8[7] = wy1 * wx1;
        }
    }
    __syncthreads();

    // ---- B fragments + bias (o = wave*16 + lr)
    bf16x8 bfrag[18];
    const unsigned short* wp = wpack + (size_t)(wave * 64 + lane) * 8;
#pragma unroll
    for (int s = 0; s < 18; s++)
        bfrag[s] = *(const bf16x8*)(wp + (size_t)s * 2048);
    float bias = bdcn[wave * 16 + lr];

    // ---- phase B: 8 lanes per px; each lane owns 8 channels, loops 9 taps
    {
        int g = lane >> 3, sub = lane & 7;
        int px = wave * 8 + g;
        const unsigned char* xtb =
            (const unsigned char*)xt + (((size_t)b * HW) << 7) + sub * 16;
        unsigned char* prow = smem + px * 1152;
        unsigned swz = (unsigned)((px & 7) << 4);
        const int* tbase = ti + px * 72;
#pragma unroll
        for (int tap = 0; tap < 9; tap++) {
            i32x4 t4 = *(const i32x4*)(tbase + tap * 8);
            f32x4 w4 = *(const f32x4*)(tbase + tap * 8 + 4);
            bf16x8 c00 = *(const bf16x8*)(xtb + t4[0]);
            bf16x8 c01 = *(const bf16x8*)(xtb + t4[1]);
            bf16x8 c10 = *(const bf16x8*)(xtb + t4[2]);
            bf16x8 c11 = *(const bf16x8*)(xtb + t4[3]);
            bf16x8 v;
#pragma unroll
            for (int j = 0; j < 8; j++) {
                float sv = w4[0] * bf2f(c00[j]) + w4[1] * bf2f(c01[j])
                         + w4[2] * bf2f(c10[j]) + w4[3] * bf2f(c11[j]);
                v[j] = (short)f2bf(sv);
            }
            *(bf16x8*)(prow + ((unsigned)(tap * 128 + sub * 16) ^ swz)) = v;
        }
    }
    __syncthreads();

    // ---- main MFMA: D[32 px][64 o], wave owns o-tile = wave
    f32x4 acc0 = {bias, bias, bias, bias};
    f32x4 acc1 = acc0;
    unsigned swzr = (unsigned)((lr & 7) << 4);
#pragma unroll
    for (int s = 0; s < 18; s++) {
        unsigned inblk = (unsigned)((s >> 1) * 128)
                       + (((unsigned)((s & 1) * 64 + hi * 16)) ^ swzr);
        bf16x8 a0 = *(const bf16x8*)(smem + lr * 1152 + inblk);
        bf16x8 a1 = *(const bf16x8*)(smem + (16 + lr) * 1152 + inblk);
        acc0 = __builtin_amdgcn_mfma_f32_16x16x32_bf16(a0, bfrag[s], acc0, 0, 0, 0);
        acc1 = __builtin_amdgcn_mfma_f32_16x16x32_bf16(a1, bfrag[s], acc1, 0, 0, 0);
    }
    __syncthreads();

    // ---- epilogue: transpose via LDS, coalesced float4 stores
    float* ldsC = (float*)smem;                    // [64][33]
    {
        int o = wave * 16 + lr;
        int pxb = hi * 4;
#pragma unroll
        for (int r = 0; r < 4; r++) {
            ldsC[o * 33 + pxb + r]      = acc0[r];
            ldsC[o * 33 + 16 + pxb + r] = acc1[r];
        }
    }
    __syncthreads();
    {
        int px4 = (tid & 7) * 4;
#pragma unroll
        for (int pass = 0; pass < 2; pass++) {
            int oo = (tid >> 3) + pass * 32;
            float4 v;
            v.x = ldsC[oo * 33 + px4];
            v.y = ldsC[oo * 33 + px4 + 1];
            v.z = ldsC[oo * 33 + px4 + 2];
            v.w = ldsC[oo * 33 + px4 + 3];
            *(float4*)(conv + ((size_t)b * OCH + oo) * HW + hwb + px4) = v;
        }
    }
}

// ---------------- kernel C: per-channel batch stats ------------------------
__global__ __launch_bounds__(256) void kstats(const float* __restrict__ conv,
                                              float* __restrict__ stats) {
    int c = blockIdx.x, tid = threadIdx.x;
    float s = 0.f, s2 = 0.f;
    for (int b = 0; b < 4; b++) {
        const float4* p = (const float4*)(conv + ((size_t)b * OCH + c) * HW);
        for (int i = tid; i < HW / 4; i += 256) {
            float4 v = p[i];
            s  += v.x + v.y + v.z + v.w;
            s2 += v.x * v.x + v.y * v.y + v.z * v.z + v.w * v.w;
        }
    }
    __shared__ float rs[256], rq[256];
    rs[tid] = s; rq[tid] = s2;
    __syncthreads();
    for (int st = 128; st > 0; st >>= 1) {
        if (tid < st) { rs[tid] += rs[tid + st]; rq[tid] += rq[tid + st]; }
        __syncthreads();
    }
    if (tid == 0) {
        float mean = rs[0] * (1.f / 65536.f);
        float var  = rq[0] * (1.f / 65536.f) - mean * mean;
        stats[c] = mean;
        stats[64 + c] = rsqrtf(var + 1e-5f);
    }
}

// ---------------- kernel D: normalize + affine + relu (in-place) -----------
__global__ __launch_bounds__(256) void kapply(float* __restrict__ conv,
                                              const float* __restrict__ stats,
                                              const float* __restrict__ gamma,
                                              const float* __restrict__ beta) {
    int t = blockIdx.x * 256 + threadIdx.x;   // < 1048576 float4s
    int c = (t >> 12) & 63;
    float mean = stats[c], rstd = stats[64 + c];
    float sc = rstd * gamma[c];
    float sh = beta[c] - mean * sc;
    float4 v = ((float4*)conv)[t];
    float4 r;
    r.x = fmaxf(v.x * sc + sh, 0.f);
    r.y = fmaxf(v.y * sc + sh, 0.f);
    r.z = fmaxf(v.z * sc + sh, 0.f);
    r.w = fmaxf(v.w * sc + sh, 0.f);
    ((float4*)conv)[t] = r;
}

// ---------------- launch ---------------------------------------------------
extern "C" void kernel_launch(void* const* d_in, const int* in_sizes, int n_in,
                              void* d_out, int out_size, void* d_ws, size_t ws_size,
                              hipStream_t stream) {
    const float* x     = (const float*)d_in[0];
    const float* woff  = (const float*)d_in[1];
    const float* boff  = (const float*)d_in[2];
    const float* wdcn  = (const float*)d_in[3];
    const float* bdcn  = (const float*)d_in[4];
    const float* gamma = (const float*)d_in[5];
    const float* beta  = (const float*)d_in[6];
    float* out = (float*)d_out;   // also holds pre-BN conv result

    // workspace layout (bytes): xt 8 MB | wpack 72 KB | woffpack 36 KB | stats
    unsigned char* ws = (unsigned char*)d_ws;
    unsigned short* xt       = (unsigned short*)ws;            // 4,194,304 ush
    unsigned short* wpack    = (unsigned short*)(ws + 8388608);//    36,864 ush
    unsigned short* woffpack = (unsigned short*)(ws + 8462336);//    18,432 ush
    float*          stats    = (float*)(ws + 8499200);         //       128 f
    // total ~8.5 MB

    hipLaunchKernelGGL(kxt,    dim3(256),  dim3(256), 0, stream, x, xt);
    hipLaunchKernelGGL(kpack,  dim3(216),  dim3(256), 0, stream, wdcn, woff, wpack, woffpack);
    hipLaunchKernelGGL(kdcn,   dim3(2048), dim3(256), 0, stream, xt, wpack, woffpack, boff, bdcn, out);
    hipLaunchKernelGGL(kstats, dim3(64),   dim3(256), 0, stream, out, stats);
    hipLaunchKernelGGL(kapply, dim3(4096), dim3(256), 0, stream, out, stats, gamma, beta);
}